// Round 7
// baseline (436.259 us; speedup 1.0000x reference)
//
#include <hip/hip_runtime.h>
#include <hip/hip_bf16.h>

typedef __attribute__((ext_vector_type(8))) short bf16x8;
typedef __attribute__((ext_vector_type(4))) float f32x4;
typedef __attribute__((ext_vector_type(2))) float f32x2;

struct Params {
  const float* x[6];
  const float* W[6];
  const float* cg;
  float* out;
  unsigned short* Wb;   // ws: W pre-swizzled to bf16 B-fragment order (4,091,904 B)
};

constexpr int NPAIRS_C[6] = {6, 15, 21, 24, 24, 21};
constexpr int POFF_C[6]   = {0, 6, 21, 42, 66, 90};
constexpr size_t WBASE_C[6] = {0, 110592, 387072, 774144, 1216512, 1658880};
constexpr int KL_C[6]   = {3456, 8640, 12096, 13824, 13824, 12096};
constexpr int LOFF_C[6] = {0, 1, 4, 9, 16, 25};   // row offset of l in xall
#define XSTRIDE 236       // floats; %32==12, %4==0 (16B-aligned rows); per-b col stride 28
#define BSTRIDE 28        // b*28 mod 32 = {0,28,24,20,16,12,8,4} — all distinct banks

constexpr int TL1[111] = {
  0,1,2,3,4,5,
  0,1,1,1,2,2,2,3,3,3,4,4,4,5,5,
  0,1,1,1,2,2,2,2,2,3,3,3,3,3,4,4,4,4,5,5,5,
  0,1,1,1,2,2,2,2,2,3,3,3,3,3,3,4,4,4,4,4,5,5,5,5,
  0,1,1,1,2,2,2,2,3,3,3,3,3,4,4,4,4,4,4,5,5,5,5,5,
  0,1,1,2,2,2,3,3,3,3,4,4,4,4,4,5,5,5,5,5,5
};
constexpr int TL2R[111] = {
  0,1,2,3,4,5,
  1,0,1,2,1,2,3,2,3,4,3,4,5,4,5,
  2,1,2,3,0,1,2,3,4,1,2,3,4,5,2,3,4,5,3,4,5,
  3,2,3,4,1,2,3,4,5,0,1,2,3,4,5,1,2,3,4,5,2,3,4,5,
  4,3,4,5,2,3,4,5,1,2,3,4,5,0,1,2,3,4,5,1,2,3,4,5,
  5,4,5,3,4,5,2,3,4,5,1,2,3,4,5,0,1,2,3,4,5
};

__constant__ int c_l1[111] = {
  0,1,2,3,4,5,
  0,1,1,1,2,2,2,3,3,3,4,4,4,5,5,
  0,1,1,1,2,2,2,2,2,3,3,3,3,3,4,4,4,4,5,5,5,
  0,1,1,1,2,2,2,2,2,3,3,3,3,3,3,4,4,4,4,4,5,5,5,5,
  0,1,1,1,2,2,2,2,3,3,3,3,3,4,4,4,4,4,4,5,5,5,5,5,
  0,1,1,2,2,2,3,3,3,3,4,4,4,4,4,5,5,5,5,5,5
};
__constant__ int c_l2[111] = {
  0,1,2,3,4,5,
  1,0,1,2,1,2,3,2,3,4,3,4,5,4,5,
  2,1,2,3,0,1,2,3,4,1,2,3,4,5,2,3,4,5,3,4,5,
  3,2,3,4,1,2,3,4,5,0,1,2,3,4,5,1,2,3,4,5,2,3,4,5,
  4,3,4,5,2,3,4,5,1,2,3,4,5,0,1,2,3,4,5,1,2,3,4,5,
  5,4,5,3,4,5,2,3,4,5,1,2,3,4,5,0,1,2,3,4,5
};
// 3-chunk groups: wave w owns chunks {GA3[w], GA3[w]+3, GA3[w]+6} — same d0, c += 4, 8
__constant__ int c_GA3[6] = {0,1,2,9,10,11};

// ---------- W swizzle: fp32 [h][k] -> bf16 B-fragment stream (verified R4) ----------
template<int L>
__device__ __forceinline__ void swz(const Params& P, int u8) {
  constexpr int KL = KL_C[L];
  constexpr int KL8 = KL / 8;
  if (u8 >= 32 * KL8) return;
  const int h  = u8 / KL8;
  const int k  = (u8 - h * KL8) * 8;
  const int pair = k / 576;
  const int kin  = k - pair * 576;
  const int kc = kin >> 5;
  const int g  = (kin >> 3) & 3;
  const float* src = P.W[L] + (size_t)h * KL + k;
  f32x4 v0 = *(const f32x4*)src;
  f32x4 v1 = *(const f32x4*)(src + 4);
  union { __hip_bfloat162 h2; unsigned int u; } z;
  unsigned int o0, o1, o2, o3;
  z.h2 = __float22bfloat162_rn(make_float2(v0.x, v0.y)); o0 = z.u;
  z.h2 = __float22bfloat162_rn(make_float2(v0.z, v0.w)); o1 = z.u;
  z.h2 = __float22bfloat162_rn(make_float2(v1.x, v1.y)); o2 = z.u;
  z.h2 = __float22bfloat162_rn(make_float2(v1.z, v1.w)); o3 = z.u;
  const size_t dst = WBASE_C[L] + (size_t)pair * 18432 + kc * 1024 + (h >> 4) * 512
                   + ((size_t)(g * 16 + (h & 15))) * 8;
  *(uint4*)(P.Wb + dst) = make_uint4(o0, o1, o2, o3);
}

__global__ __launch_bounds__(256)
void swizzle_W(Params P) {
  const int u8 = blockIdx.x * 256 + threadIdx.x;
  switch (blockIdx.y) {
    case 0: swz<0>(P, u8); break;
    case 1: swz<1>(P, u8); break;
    case 2: swz<2>(P, u8); break;
    case 3: swz<3>(P, u8); break;
    case 4: swz<4>(P, u8); break;
    default: swz<5>(P, u8); break;
  }
}

// ---------- LDS layout (float units) ----------
// xall: [1 guard + 36 data + 1 guard rows][XSTRIDE] = 38*236 = 8968 floats
//   data row of (l,i) = 1 + LOFF[l] + i; col = b*28 + c (c<24). Guards never zeroed:
//   reads there are multiplied by staged cg==0 (poison 0xAA = finite float -> 0*x = 0).
#define XALL_F 0
#define CG_F   8968       // [2][NP][12] f32 <= 576
#define RED_F  9544       // [6][16][32] f32 = 3072
#define SMEM_FLOATS 12616 // 50,464 B -> 3 blocks/CU

template<int L, int MP0>
__device__ __forceinline__ void body(const Params& P, const int btile) {
  constexpr int NP  = NPAIRS_C[L];
  constexpr int OFF = POFF_C[L];
  extern __shared__ float smem[];
  float* xall  = smem + XALL_F;
  float* cgall = smem + CG_F;
  float* red   = smem + RED_F;

  const int t    = threadIdx.x;          // 384 threads = 6 waves
  const int lane = t & 63;
  const int w    = t >> 6;               // wave = 3-chunk group id (0..5)
  const int q8   = lane >> 4;            // A-frag k-quad
  const int rI   = lane & 15;            // A-frag row: b = rI&7, mpL = rI>>3
  const int b    = rI & 7;
  const int mpL  = rI >> 3;
  const int b0   = btile * 8;

  // ---- stage all x, transposed: xall[(1+LOFF[l]+i)*XSTRIDE + b*28 + c] ----
#pragma unroll
  for (int l = 0; l < 6; ++l) {
    const int n = 2 * l + 1;
    const float* src = P.x[l] + (size_t)b0 * 24 * n;
    const int tot = 8 * 24 * n;
    for (int e = t; e < tot; e += 384) {
      const int bc = e / n;                  // compile-time divisor
      const int i  = e - bc * n;
      const int bb = bc / 24;
      const int cc = bc - 24 * bb;
      xall[(1 + LOFF_C[l] + i) * XSTRIDE + bb * BSTRIDE + cc] = src[e];
    }
  }
  // ---- stage cg diagonals for MP0 and MP0+1 (zeros where invalid) ----
  for (int e = t; e < 2 * NP * 12; e += 384) {
    const int i  = e % 12;
    const int r  = e / 12;
    const int pi = r % NP;
    const int mL = r / NP;
    const int l1 = c_l1[OFF + pi], l2 = c_l2[OFF + pi];
    const int mp = MP0 + mL;
    const int j  = mp + l1 + l2 - L - i;
    float v = 0.f;
    if (mp <= 2 * L && i <= 2 * l1 && j >= 0 && j <= 2 * l2)
      v = P.cg[((size_t)(((l1 * 6 + l2) * 6 + L) * 11 + mp) * 11 + i) * 11 + j];
    cgall[(mL * NP + pi) * 12 + i] = v;
  }
  __syncthreads();

  f32x4 accC0 = {0.f, 0.f, 0.f, 0.f};   // h 0..15
  f32x4 accC1 = {0.f, 0.f, 0.f, 0.f};   // h 16..31

  // this wave's 3-chunk group
  const int kcA = c_GA3[w];
  const int k0  = kcA * 32 + q8 * 8;
  const int cA  = k0 / 24;
  const int d0  = k0 - cA * 24;          // in {0,8,16}
  const int bcol = b * BSTRIDE;
  // per-lane bases (mpL folded into x2 row)
  const float* x2l = xall + (size_t)(1 + mpL) * XSTRIDE + bcol + d0;  // + (R2+mK0w-i)*XSTRIDE
  const float* x1l = xall + (size_t)1 * XSTRIDE + bcol + cA;          // + (R1+i)*XSTRIDE

#pragma unroll
  for (int pi = 0; pi < NP; ++pi) {
    const int l1 = TL1[OFF + pi], l2 = TL2R[OFF + pi];   // compile-time after unroll
    const int n1 = 2 * l1 + 1, n2 = 2 * l2 + 1;
    const int R1 = LOFF_C[l1], R2 = LOFF_C[l2];
    const int mK0w = MP0 + l1 + l2 - L;                  // compile-time
    const int i0 = (mK0w - (n2 - 1)) > 0 ? (mK0w - (n2 - 1)) : 0;
    const int i1 = (n1 - 1) < (mK0w + 1) ? (n1 - 1) : (mK0w + 1);

    // prefetch bf16 B-fragments (L2-resident Wb)
    const unsigned short* wbp = P.Wb + WBASE_C[L] + (size_t)pi * 18432 + lane * 8;
    const bf16x8 wfA0 = *(const bf16x8*)(wbp + kcA * 1024);
    const bf16x8 wfA1 = *(const bf16x8*)(wbp + kcA * 1024 + 512);
    const bf16x8 wfB0 = *(const bf16x8*)(wbp + (kcA + 3) * 1024);
    const bf16x8 wfB1 = *(const bf16x8*)(wbp + (kcA + 3) * 1024 + 512);
    const bf16x8 wfC0 = *(const bf16x8*)(wbp + (kcA + 6) * 1024);
    const bf16x8 wfC1 = *(const bf16x8*)(wbp + (kcA + 6) * 1024 + 512);

    f32x2 pA[4], pB[4], pC[4];
#pragma unroll
    for (int dd = 0; dd < 4; ++dd) {
      pA[dd] = (f32x2){0.f, 0.f};
      pB[dd] = (f32x2){0.f, 0.f};
      pC[dd] = (f32x2){0.f, 0.f};
    }

    const float* cgp  = cgall + (mpL * NP + pi) * 12;
    const float* x2pp = x2l + (size_t)(R2 + mK0w) * XSTRIDE;  // - i*XSTRIDE per step
    const float* x1pp = x1l + (size_t)R1 * XSTRIDE;           // + i*XSTRIDE per step
    // j = mK0l - i in [-1, n2] by construction -> guard rows cover; cg==0 kills invalid terms
#pragma unroll
    for (int i = i0; i <= i1; ++i) {
      const float cgv = cgp[i];
      const float* x2p = x2pp - i * XSTRIDE;   // static offsets after unroll
      f32x2 xv[4];
      *(f32x4*)&xv[0] = *(const f32x4*)x2p;
      *(f32x4*)&xv[2] = *(const f32x4*)(x2p + 4);
      const float* x1p = x1pp + i * XSTRIDE;
      const float sA = cgv * x1p[0];
      const float sB = cgv * x1p[4];
      const float sC = cgv * x1p[8];
      const f32x2 svA = {sA, sA}, svB = {sB, sB}, svC = {sC, sC};
#pragma unroll
      for (int dd = 0; dd < 4; ++dd) {
        pA[dd] += svA * xv[dd];
        pB[dd] += svB * xv[dd];
        pC[dd] += svC * xv[dd];
      }
    }
    // pack A-fragments
    union { unsigned int u[4]; bf16x8 v; } zA, zB, zC;
#pragma unroll
    for (int dd = 0; dd < 4; ++dd) {
      union { __hip_bfloat162 h2; unsigned int u; } z;
      z.h2 = __float22bfloat162_rn(make_float2(pA[dd].x, pA[dd].y)); zA.u[dd] = z.u;
      z.h2 = __float22bfloat162_rn(make_float2(pB[dd].x, pB[dd].y)); zB.u[dd] = z.u;
      z.h2 = __float22bfloat162_rn(make_float2(pC[dd].x, pC[dd].y)); zC.u[dd] = z.u;
    }
    accC0 = __builtin_amdgcn_mfma_f32_16x16x32_bf16(zA.v, wfA0, accC0, 0, 0, 0);
    accC0 = __builtin_amdgcn_mfma_f32_16x16x32_bf16(zB.v, wfB0, accC0, 0, 0, 0);
    accC0 = __builtin_amdgcn_mfma_f32_16x16x32_bf16(zC.v, wfC0, accC0, 0, 0, 0);
    accC1 = __builtin_amdgcn_mfma_f32_16x16x32_bf16(zA.v, wfA1, accC1, 0, 0, 0);
    accC1 = __builtin_amdgcn_mfma_f32_16x16x32_bf16(zB.v, wfB1, accC1, 0, 0, 0);
    accC1 = __builtin_amdgcn_mfma_f32_16x16x32_bf16(zC.v, wfC1, accC1, 0, 0, 0);
  }

  // ---- cross-wave k-reduction over 6 waves ----
  {
    const int col16 = lane & 15;      // D: col = h (lo half), row = (lane>>4)*4+reg
    const int rbase = w * 16 + (lane >> 4) * 4;
#pragma unroll
    for (int r = 0; r < 4; ++r) {
      red[(rbase + r) * 32 + col16]      = accC0[r];
      red[(rbase + r) * 32 + 16 + col16] = accC1[r];
    }
  }
  __syncthreads();
  for (int idx = t; idx < 512; idx += 384) {
    const int row = idx >> 5, h = idx & 31;   // 512: 16 rows x 32 h
    float v = 0.f;
#pragma unroll
    for (int ww = 0; ww < 6; ++ww) v += red[ww * 512 + row * 32 + h];
    const int ob = row & 7, omL = row >> 3;
    const int mp = MP0 + omL;
    if (mp <= 2 * L)
      P.out[(size_t)(b0 + ob) * 1152 + h * 36 + L * L + mp] = v;
  }
}

__global__ __launch_bounds__(384, 5)
void CGLayer_main(Params P) {
  const int bt = blockIdx.y;
  switch (blockIdx.x) {   // heavy-L first for dispatch balance
    case 0:  body<5, 0>(P, bt); break;
    case 1:  body<5, 2>(P, bt); break;
    case 2:  body<5, 4>(P, bt); break;
    case 3:  body<5, 6>(P, bt); break;
    case 4:  body<5, 8>(P, bt); break;
    case 5:  body<5,10>(P, bt); break;
    case 6:  body<4, 0>(P, bt); break;
    case 7:  body<4, 2>(P, bt); break;
    case 8:  body<4, 4>(P, bt); break;
    case 9:  body<4, 6>(P, bt); break;
    case 10: body<4, 8>(P, bt); break;
    case 11: body<3, 0>(P, bt); break;
    case 12: body<3, 2>(P, bt); break;
    case 13: body<3, 4>(P, bt); break;
    case 14: body<3, 6>(P, bt); break;
    case 15: body<2, 0>(P, bt); break;
    case 16: body<2, 2>(P, bt); break;
    case 17: body<2, 4>(P, bt); break;
    case 18: body<1, 0>(P, bt); break;
    case 19: body<1, 2>(P, bt); break;
    default: body<0, 0>(P, bt); break;
  }
}

extern "C" void kernel_launch(void* const* d_in, const int* in_sizes, int n_in,
                              void* d_out, int out_size, void* d_ws, size_t ws_size,
                              hipStream_t stream) {
  Params P;
  for (int i = 0; i < 6; ++i) P.x[i] = (const float*)d_in[i];
  for (int i = 0; i < 6; ++i) P.W[i] = (const float*)d_in[6 + i];
  P.cg  = (const float*)d_in[12];
  P.out = (float*)d_out;
  P.Wb  = (unsigned short*)d_ws;   // needs 4,091,904 bytes

  dim3 sg(216, 6);
  swizzle_W<<<sg, 256, 0, stream>>>(P);
  dim3 grid(21, 32);
  CGLayer_main<<<grid, 384, SMEM_FLOATS * sizeof(float), stream>>>(P);
}

// Round 8
// 253.816 us; speedup vs baseline: 1.7188x; 1.7188x over previous
//
#include <hip/hip_runtime.h>
#include <hip/hip_bf16.h>

typedef __attribute__((ext_vector_type(8))) short bf16x8;
typedef __attribute__((ext_vector_type(4))) float f32x4;
typedef __attribute__((ext_vector_type(2))) float f32x2;

struct Params {
  const float* x[6];
  const float* W[6];
  const float* cg;
  float* out;
  unsigned short* Wb;   // ws: W pre-swizzled to bf16 B-fragment order (4,091,904 B)
};

constexpr int NPAIRS_C[6] = {6, 15, 21, 24, 24, 21};
constexpr int POFF_C[6]   = {0, 6, 21, 42, 66, 90};
constexpr size_t WBASE_C[6] = {0, 110592, 387072, 774144, 1216512, 1658880};
constexpr int KL_C[6]   = {3456, 8640, 12096, 13824, 13824, 12096};
constexpr int LOFF_C[6] = {0, 1, 4, 9, 16, 25};   // row offset of l in xall
#define XSTRIDE 236       // floats; %32==12, %4==0 (16B-aligned rows); per-b col stride 28
#define BSTRIDE 28        // b*28 mod 32 = {0,28,24,20,16,12,8,4} — all distinct banks

constexpr int TL1[111] = {
  0,1,2,3,4,5,
  0,1,1,1,2,2,2,3,3,3,4,4,4,5,5,
  0,1,1,1,2,2,2,2,2,3,3,3,3,3,4,4,4,4,5,5,5,
  0,1,1,1,2,2,2,2,2,3,3,3,3,3,3,4,4,4,4,4,5,5,5,5,
  0,1,1,1,2,2,2,2,3,3,3,3,3,4,4,4,4,4,4,5,5,5,5,5,
  0,1,1,2,2,2,3,3,3,3,4,4,4,4,4,5,5,5,5,5,5
};
constexpr int TL2R[111] = {
  0,1,2,3,4,5,
  1,0,1,2,1,2,3,2,3,4,3,4,5,4,5,
  2,1,2,3,0,1,2,3,4,1,2,3,4,5,2,3,4,5,3,4,5,
  3,2,3,4,1,2,3,4,5,0,1,2,3,4,5,1,2,3,4,5,2,3,4,5,
  4,3,4,5,2,3,4,5,1,2,3,4,5,0,1,2,3,4,5,1,2,3,4,5,
  5,4,5,3,4,5,2,3,4,5,1,2,3,4,5,0,1,2,3,4,5
};

__constant__ int c_l1[111] = {
  0,1,2,3,4,5,
  0,1,1,1,2,2,2,3,3,3,4,4,4,5,5,
  0,1,1,1,2,2,2,2,2,3,3,3,3,3,4,4,4,4,5,5,5,
  0,1,1,1,2,2,2,2,2,3,3,3,3,3,3,4,4,4,4,4,5,5,5,5,
  0,1,1,1,2,2,2,2,3,3,3,3,3,4,4,4,4,4,4,5,5,5,5,5,
  0,1,1,2,2,2,3,3,3,3,4,4,4,4,4,5,5,5,5,5,5
};
__constant__ int c_l2[111] = {
  0,1,2,3,4,5,
  1,0,1,2,1,2,3,2,3,4,3,4,5,4,5,
  2,1,2,3,0,1,2,3,4,1,2,3,4,5,2,3,4,5,3,4,5,
  3,2,3,4,1,2,3,4,5,0,1,2,3,4,5,1,2,3,4,5,2,3,4,5,
  4,3,4,5,2,3,4,5,1,2,3,4,5,0,1,2,3,4,5,1,2,3,4,5,
  5,4,5,3,4,5,2,3,4,5,1,2,3,4,5,0,1,2,3,4,5
};
// 3-chunk groups: wave w owns chunks {GA3[w], GA3[w]+3, GA3[w]+6} — same d0, c += 4, 8
__constant__ int c_GA3[6] = {0,1,2,9,10,11};

// ---------- W swizzle: fp32 [h][k] -> bf16 B-fragment stream (verified R4) ----------
template<int L>
__device__ __forceinline__ void swz(const Params& P, int u8) {
  constexpr int KL = KL_C[L];
  constexpr int KL8 = KL / 8;
  if (u8 >= 32 * KL8) return;
  const int h  = u8 / KL8;
  const int k  = (u8 - h * KL8) * 8;
  const int pair = k / 576;
  const int kin  = k - pair * 576;
  const int kc = kin >> 5;
  const int g  = (kin >> 3) & 3;
  const float* src = P.W[L] + (size_t)h * KL + k;
  f32x4 v0 = *(const f32x4*)src;
  f32x4 v1 = *(const f32x4*)(src + 4);
  union { __hip_bfloat162 h2; unsigned int u; } z;
  unsigned int o0, o1, o2, o3;
  z.h2 = __float22bfloat162_rn(make_float2(v0.x, v0.y)); o0 = z.u;
  z.h2 = __float22bfloat162_rn(make_float2(v0.z, v0.w)); o1 = z.u;
  z.h2 = __float22bfloat162_rn(make_float2(v1.x, v1.y)); o2 = z.u;
  z.h2 = __float22bfloat162_rn(make_float2(v1.z, v1.w)); o3 = z.u;
  const size_t dst = WBASE_C[L] + (size_t)pair * 18432 + kc * 1024 + (h >> 4) * 512
                   + ((size_t)(g * 16 + (h & 15))) * 8;
  *(uint4*)(P.Wb + dst) = make_uint4(o0, o1, o2, o3);
}

__global__ __launch_bounds__(256)
void swizzle_W(Params P) {
  const int u8 = blockIdx.x * 256 + threadIdx.x;
  switch (blockIdx.y) {
    case 0: swz<0>(P, u8); break;
    case 1: swz<1>(P, u8); break;
    case 2: swz<2>(P, u8); break;
    case 3: swz<3>(P, u8); break;
    case 4: swz<4>(P, u8); break;
    default: swz<5>(P, u8); break;
  }
}

// ---------- LDS layout (float units) ----------
// xall: [1 guard + 36 data + 1 guard rows][XSTRIDE] = 38*236 = 8968 floats
//   data row of (l,i) = 1 + LOFF[l] + i; col = b*28 + c (c<24). Guard rows are ZEROED
//   (uninitialized LDS could hold NaN; 0*NaN = NaN would corrupt the cg==0 masking).
#define XALL_F 0
#define CG_F   8968       // [2][NP][12] f32 <= 576
#define RED_F  9544       // [6][16][32] f32 = 3072
#define SMEM_FLOATS 12616 // 50,464 B -> 3 blocks/CU

template<int L, int MP0>
__device__ __forceinline__ void body(const Params& P, const int btile) {
  constexpr int NP  = NPAIRS_C[L];
  constexpr int OFF = POFF_C[L];
  extern __shared__ float smem[];
  float* xall  = smem + XALL_F;
  float* cgall = smem + CG_F;
  float* red   = smem + RED_F;

  const int t    = threadIdx.x;          // 384 threads = 6 waves
  const int lane = t & 63;
  const int w    = t >> 6;               // wave = 3-chunk group id (0..5)
  const int q8   = lane >> 4;            // A-frag k-quad
  const int rI   = lane & 15;            // A-frag row: b = rI&7, mpL = rI>>3
  const int b    = rI & 7;
  const int mpL  = rI >> 3;
  const int b0   = btile * 8;

  // ---- zero guard rows (rows 0 and 37) ----
  for (int e = t; e < 2 * XSTRIDE; e += 384) {
    const int r = (e < XSTRIDE) ? 0 : 37;
    xall[r * XSTRIDE + (e % XSTRIDE)] = 0.f;
  }
  // ---- stage all x, transposed: xall[(1+LOFF[l]+i)*XSTRIDE + b*28 + c] ----
#pragma unroll
  for (int l = 0; l < 6; ++l) {
    const int n = 2 * l + 1;
    const float* src = P.x[l] + (size_t)b0 * 24 * n;
    const int tot = 8 * 24 * n;
    for (int e = t; e < tot; e += 384) {
      const int bc = e / n;                  // compile-time divisor
      const int i  = e - bc * n;
      const int bb = bc / 24;
      const int cc = bc - 24 * bb;
      xall[(1 + LOFF_C[l] + i) * XSTRIDE + bb * BSTRIDE + cc] = src[e];
    }
  }
  // ---- stage cg diagonals for MP0 and MP0+1 (zeros where invalid) ----
  for (int e = t; e < 2 * NP * 12; e += 384) {
    const int i  = e % 12;
    const int r  = e / 12;
    const int pi = r % NP;
    const int mL = r / NP;
    const int l1 = c_l1[OFF + pi], l2 = c_l2[OFF + pi];
    const int mp = MP0 + mL;
    const int j  = mp + l1 + l2 - L - i;
    float v = 0.f;
    if (mp <= 2 * L && i <= 2 * l1 && j >= 0 && j <= 2 * l2)
      v = P.cg[((size_t)(((l1 * 6 + l2) * 6 + L) * 11 + mp) * 11 + i) * 11 + j];
    cgall[(mL * NP + pi) * 12 + i] = v;
  }
  __syncthreads();

  f32x4 accC0 = {0.f, 0.f, 0.f, 0.f};   // h 0..15
  f32x4 accC1 = {0.f, 0.f, 0.f, 0.f};   // h 16..31

  // this wave's 3-chunk group
  const int kcA = c_GA3[w];
  const int k0  = kcA * 32 + q8 * 8;
  const int cA  = k0 / 24;
  const int d0  = k0 - cA * 24;          // in {0,8,16}
  const int bcol = b * BSTRIDE;
  // per-lane bases (mpL folded into x2 row)
  const float* x2l = xall + (size_t)(1 + mpL) * XSTRIDE + bcol + d0;  // + (R2+mK0w-i)*XSTRIDE
  const float* x1l = xall + (size_t)1 * XSTRIDE + bcol + cA;          // + (R1+i)*XSTRIDE

#pragma unroll
  for (int pi = 0; pi < NP; ++pi) {
    const int l1 = TL1[OFF + pi], l2 = TL2R[OFF + pi];   // compile-time after unroll
    const int n1 = 2 * l1 + 1, n2 = 2 * l2 + 1;
    const int R1 = LOFF_C[l1], R2 = LOFF_C[l2];
    const int mK0w = MP0 + l1 + l2 - L;                  // compile-time
    const int i0 = (mK0w - (n2 - 1)) > 0 ? (mK0w - (n2 - 1)) : 0;
    const int i1 = (n1 - 1) < (mK0w + 1) ? (n1 - 1) : (mK0w + 1);

    // prefetch bf16 B-fragments (L2-resident Wb)
    const unsigned short* wbp = P.Wb + WBASE_C[L] + (size_t)pi * 18432 + lane * 8;
    const bf16x8 wfA0 = *(const bf16x8*)(wbp + kcA * 1024);
    const bf16x8 wfA1 = *(const bf16x8*)(wbp + kcA * 1024 + 512);
    const bf16x8 wfB0 = *(const bf16x8*)(wbp + (kcA + 3) * 1024);
    const bf16x8 wfB1 = *(const bf16x8*)(wbp + (kcA + 3) * 1024 + 512);
    const bf16x8 wfC0 = *(const bf16x8*)(wbp + (kcA + 6) * 1024);
    const bf16x8 wfC1 = *(const bf16x8*)(wbp + (kcA + 6) * 1024 + 512);

    f32x2 pA[4], pB[4], pC[4];
#pragma unroll
    for (int dd = 0; dd < 4; ++dd) {
      pA[dd] = (f32x2){0.f, 0.f};
      pB[dd] = (f32x2){0.f, 0.f};
      pC[dd] = (f32x2){0.f, 0.f};
    }

    const float* cgp  = cgall + (mpL * NP + pi) * 12;
    const float* x2pp = x2l + (size_t)(R2 + mK0w) * XSTRIDE;  // - i*XSTRIDE per step
    const float* x1pp = x1l + (size_t)R1 * XSTRIDE;           // + i*XSTRIDE per step
    // j = mK0l - i in [-1, n2] by construction -> guard rows cover; cg==0 kills invalid terms.
    // unroll 1: R7's full flatten spilled to scratch (WRITE_SIZE 6->369 MB) — keep bodies small.
#pragma unroll 1
    for (int i = i0; i <= i1; ++i) {
      const float cgv = cgp[i];
      const float* x2p = x2pp - i * XSTRIDE;
      f32x2 xv[4];
      *(f32x4*)&xv[0] = *(const f32x4*)x2p;
      *(f32x4*)&xv[2] = *(const f32x4*)(x2p + 4);
      const float* x1p = x1pp + i * XSTRIDE;
      const float sA = cgv * x1p[0];
      const float sB = cgv * x1p[4];
      const float sC = cgv * x1p[8];
      const f32x2 svA = {sA, sA}, svB = {sB, sB}, svC = {sC, sC};
#pragma unroll
      for (int dd = 0; dd < 4; ++dd) {
        pA[dd] += svA * xv[dd];
        pB[dd] += svB * xv[dd];
        pC[dd] += svC * xv[dd];
      }
    }
    // pack A-fragments
    union { unsigned int u[4]; bf16x8 v; } zA, zB, zC;
#pragma unroll
    for (int dd = 0; dd < 4; ++dd) {
      union { __hip_bfloat162 h2; unsigned int u; } z;
      z.h2 = __float22bfloat162_rn(make_float2(pA[dd].x, pA[dd].y)); zA.u[dd] = z.u;
      z.h2 = __float22bfloat162_rn(make_float2(pB[dd].x, pB[dd].y)); zB.u[dd] = z.u;
      z.h2 = __float22bfloat162_rn(make_float2(pC[dd].x, pC[dd].y)); zC.u[dd] = z.u;
    }
    accC0 = __builtin_amdgcn_mfma_f32_16x16x32_bf16(zA.v, wfA0, accC0, 0, 0, 0);
    accC0 = __builtin_amdgcn_mfma_f32_16x16x32_bf16(zB.v, wfB0, accC0, 0, 0, 0);
    accC0 = __builtin_amdgcn_mfma_f32_16x16x32_bf16(zC.v, wfC0, accC0, 0, 0, 0);
    accC1 = __builtin_amdgcn_mfma_f32_16x16x32_bf16(zA.v, wfA1, accC1, 0, 0, 0);
    accC1 = __builtin_amdgcn_mfma_f32_16x16x32_bf16(zB.v, wfB1, accC1, 0, 0, 0);
    accC1 = __builtin_amdgcn_mfma_f32_16x16x32_bf16(zC.v, wfC1, accC1, 0, 0, 0);
  }

  // ---- cross-wave k-reduction over 6 waves ----
  {
    const int col16 = lane & 15;      // D: col = h (lo half), row = (lane>>4)*4+reg
    const int rbase = w * 16 + (lane >> 4) * 4;
#pragma unroll
    for (int r = 0; r < 4; ++r) {
      red[(rbase + r) * 32 + col16]      = accC0[r];
      red[(rbase + r) * 32 + 16 + col16] = accC1[r];
    }
  }
  __syncthreads();
  for (int idx = t; idx < 512; idx += 384) {
    const int row = idx >> 5, h = idx & 31;   // 512: 16 rows x 32 h
    float v = 0.f;
#pragma unroll
    for (int ww = 0; ww < 6; ++ww) v += red[ww * 512 + row * 32 + h];
    const int ob = row & 7, omL = row >> 3;
    const int mp = MP0 + omL;
    if (mp <= 2 * L)
      P.out[(size_t)(b0 + ob) * 1152 + h * 36 + L * L + mp] = v;
  }
}

__global__ __launch_bounds__(384, 5)
void CGLayer_main(Params P) {
  const int bt = blockIdx.y;
  switch (blockIdx.x) {   // heavy-L first for dispatch balance
    case 0:  body<5, 0>(P, bt); break;
    case 1:  body<5, 2>(P, bt); break;
    case 2:  body<5, 4>(P, bt); break;
    case 3:  body<5, 6>(P, bt); break;
    case 4:  body<5, 8>(P, bt); break;
    case 5:  body<5,10>(P, bt); break;
    case 6:  body<4, 0>(P, bt); break;
    case 7:  body<4, 2>(P, bt); break;
    case 8:  body<4, 4>(P, bt); break;
    case 9:  body<4, 6>(P, bt); break;
    case 10: body<4, 8>(P, bt); break;
    case 11: body<3, 0>(P, bt); break;
    case 12: body<3, 2>(P, bt); break;
    case 13: body<3, 4>(P, bt); break;
    case 14: body<3, 6>(P, bt); break;
    case 15: body<2, 0>(P, bt); break;
    case 16: body<2, 2>(P, bt); break;
    case 17: body<2, 4>(P, bt); break;
    case 18: body<1, 0>(P, bt); break;
    case 19: body<1, 2>(P, bt); break;
    default: body<0, 0>(P, bt); break;
  }
}

extern "C" void kernel_launch(void* const* d_in, const int* in_sizes, int n_in,
                              void* d_out, int out_size, void* d_ws, size_t ws_size,
                              hipStream_t stream) {
  Params P;
  for (int i = 0; i < 6; ++i) P.x[i] = (const float*)d_in[i];
  for (int i = 0; i < 6; ++i) P.W[i] = (const float*)d_in[6 + i];
  P.cg  = (const float*)d_in[12];
  P.out = (float*)d_out;
  P.Wb  = (unsigned short*)d_ws;   // needs 4,091,904 bytes

  dim3 sg(216, 6);
  swizzle_W<<<sg, 256, 0, stream>>>(P);
  dim3 grid(21, 32);
  CGLayer_main<<<grid, 384, SMEM_FLOATS * sizeof(float), stream>>>(P);
}

// Round 9
// 161.691 us; speedup vs baseline: 2.6981x; 1.5698x over previous
//
#include <hip/hip_runtime.h>
#include <hip/hip_bf16.h>

typedef __attribute__((ext_vector_type(8))) short bf16x8;
typedef __attribute__((ext_vector_type(4))) float f32x4;
typedef __attribute__((ext_vector_type(2))) float f32x2;

struct Params {
  const float* x[6];
  const float* W[6];
  const float* cg;
  float* out;
  unsigned short* Wb;   // ws: W pre-swizzled to bf16 B-fragment order (4,091,904 B)
};

constexpr int NPAIRS_C[6] = {6, 15, 21, 24, 24, 21};
constexpr int POFF_C[6]   = {0, 6, 21, 42, 66, 90};
constexpr size_t WBASE_C[6] = {0, 110592, 387072, 774144, 1216512, 1658880};
constexpr int KL_C[6]   = {3456, 8640, 12096, 13824, 13824, 12096};
#define XSTRIDE 236       // floats; %32==12, %4==0 (16B-aligned rows)
#define BSTRIDE 28        // b*28 mod 32 all distinct -> conflict-free b128 phases

__constant__ int c_l1[111] = {
  0,1,2,3,4,5,
  0,1,1,1,2,2,2,3,3,3,4,4,4,5,5,
  0,1,1,1,2,2,2,2,2,3,3,3,3,3,4,4,4,4,5,5,5,
  0,1,1,1,2,2,2,2,2,3,3,3,3,3,3,4,4,4,4,4,5,5,5,5,
  0,1,1,1,2,2,2,2,3,3,3,3,3,4,4,4,4,4,4,5,5,5,5,5,
  0,1,1,2,2,2,3,3,3,3,4,4,4,4,4,5,5,5,5,5,5
};
__constant__ int c_l2[111] = {
  0,1,2,3,4,5,
  1,0,1,2,1,2,3,2,3,4,3,4,5,4,5,
  2,1,2,3,0,1,2,3,4,1,2,3,4,5,2,3,4,5,3,4,5,
  3,2,3,4,1,2,3,4,5,0,1,2,3,4,5,1,2,3,4,5,2,3,4,5,
  4,3,4,5,2,3,4,5,1,2,3,4,5,0,1,2,3,4,5,1,2,3,4,5,
  5,4,5,3,4,5,2,3,4,5,1,2,3,4,5,0,1,2,3,4,5
};
__constant__ int c_loff[6] = {0, 1, 4, 9, 16, 25};
// 21 (L, mp0) combos, heavy-L first
__constant__ int c_mb_l[21]  = {5,5,5,5,5,5, 4,4,4,4,4, 3,3,3,3, 2,2,2, 1,1, 0};
__constant__ int c_mb_m0[21] = {0,2,4,6,8,10, 0,2,4,6,8, 0,2,4,6, 0,2,4, 0,2, 0};
// 3-chunk groups: wave w owns chunks {GA3[w], GA3[w]+3, GA3[w]+6} — same d0, c += 4, 8
__constant__ int c_GA3[6] = {0,1,2,9,10,11};

// ---------- W swizzle: fp32 [h][k] -> bf16 B-fragment stream (verified R4) ----------
template<int L>
__device__ __forceinline__ void swz(const Params& P, int u8) {
  constexpr int KL = KL_C[L];
  constexpr int KL8 = KL / 8;
  if (u8 >= 32 * KL8) return;
  const int h  = u8 / KL8;
  const int k  = (u8 - h * KL8) * 8;
  const int pair = k / 576;
  const int kin  = k - pair * 576;
  const int kc = kin >> 5;
  const int g  = (kin >> 3) & 3;
  const float* src = P.W[L] + (size_t)h * KL + k;
  f32x4 v0 = *(const f32x4*)src;
  f32x4 v1 = *(const f32x4*)(src + 4);
  union { __hip_bfloat162 h2; unsigned int u; } z;
  unsigned int o0, o1, o2, o3;
  z.h2 = __float22bfloat162_rn(make_float2(v0.x, v0.y)); o0 = z.u;
  z.h2 = __float22bfloat162_rn(make_float2(v0.z, v0.w)); o1 = z.u;
  z.h2 = __float22bfloat162_rn(make_float2(v1.x, v1.y)); o2 = z.u;
  z.h2 = __float22bfloat162_rn(make_float2(v1.z, v1.w)); o3 = z.u;
  const size_t dst = WBASE_C[L] + (size_t)pair * 18432 + kc * 1024 + (h >> 4) * 512
                   + ((size_t)(g * 16 + (h & 15))) * 8;
  *(uint4*)(P.Wb + dst) = make_uint4(o0, o1, o2, o3);
}

__global__ __launch_bounds__(256)
void swizzle_W(Params P) {
  const int u8 = blockIdx.x * 256 + threadIdx.x;
  switch (blockIdx.y) {
    case 0: swz<0>(P, u8); break;
    case 1: swz<1>(P, u8); break;
    case 2: swz<2>(P, u8); break;
    case 3: swz<3>(P, u8); break;
    case 4: swz<4>(P, u8); break;
    default: swz<5>(P, u8); break;
  }
}

// ---------- LDS layout (float units) ----------
// xall: [1 guard + 36 data + 1 guard rows][XSTRIDE] = 38*236 = 8968 floats
//   data row (l,i) = 1 + loff[l] + i; col = b*28 + c (c<24). Guard rows ZEROED
//   (j can hit -1 / n2 at the extremes; interior overreads land in adjacent l's
//   finite data and are killed by staged cg==0).
// red ([6][16][32] = 3072 floats) ALIASES xall after the pair loop (extra barrier).
#define XALL_F 0
#define CG_F   8968       // [2][NP][12] f32 <= 576
#define SMEM_FLOATS 9544  // 38,176 B -> 4 blocks/CU

template<int L>
__device__ __forceinline__ void body(const Params& P, const int mp0, const int btile,
                                     const int half) {
  constexpr int NP  = NPAIRS_C[L];
  constexpr int OFF = POFF_C[L];
  extern __shared__ float smem[];
  float* xall  = smem + XALL_F;
  float* cgall = smem + CG_F;
  float* red   = smem + XALL_F;          // alias (used only after barrier)

  const int t    = threadIdx.x;          // 384 threads = 6 waves
  const int lane = t & 63;
  const int w    = t >> 6;               // wave = 3-chunk group id (0..5)
  const int q8   = lane >> 4;            // A-frag k-quad
  const int rI   = lane & 15;            // A-frag row: b = rI&7, mpL = rI>>3
  const int b    = rI & 7;
  const int mpL  = rI >> 3;
  const int b0   = btile * 8;
  const int p0   = half ? NP / 2 : 0;    // this block's pair range
  const int p1   = half ? NP : NP / 2;

  // ---- zero guard rows (rows 0 and 37) ----
  for (int e = t; e < 2 * XSTRIDE; e += 384) {
    const int r = (e < XSTRIDE) ? 0 : 37;
    xall[r * XSTRIDE + (e % XSTRIDE)] = 0.f;
  }
  // ---- stage all x, transposed: xall[(1+loff[l]+i)*XSTRIDE + b*28 + c] ----
#pragma unroll
  for (int l = 0; l < 6; ++l) {
    const int n = 2 * l + 1;
    const float* src = P.x[l] + (size_t)b0 * 24 * n;
    const int tot = 8 * 24 * n;
    for (int e = t; e < tot; e += 384) {
      const int bc = e / n;                  // compile-time divisor
      const int i  = e - bc * n;
      const int bb = bc / 24;
      const int cc = bc - 24 * bb;
      xall[(1 + c_loff[l] + i) * XSTRIDE + bb * BSTRIDE + cc] = src[e];
    }
  }
  // ---- stage cg diagonals for mp0, mp0+1 (zeros where invalid) ----
  for (int e = t; e < 2 * NP * 12; e += 384) {
    const int i  = e % 12;
    const int r  = e / 12;
    const int pi = r % NP;
    const int mL = r / NP;
    const int l1 = c_l1[OFF + pi], l2 = c_l2[OFF + pi];
    const int mp = mp0 + mL;
    const int j  = mp + l1 + l2 - L - i;
    float v = 0.f;
    if (mp <= 2 * L && i <= 2 * l1 && j >= 0 && j <= 2 * l2)
      v = P.cg[((size_t)(((l1 * 6 + l2) * 6 + L) * 11 + mp) * 11 + i) * 11 + j];
    cgall[(mL * NP + pi) * 12 + i] = v;
  }
  __syncthreads();

  f32x4 accC0 = {0.f, 0.f, 0.f, 0.f};   // h 0..15
  f32x4 accC1 = {0.f, 0.f, 0.f, 0.f};   // h 16..31

  // this wave's 3-chunk group
  const int kcA = c_GA3[w];
  const int k0  = kcA * 32 + q8 * 8;
  const int cA  = k0 / 24;
  const int d0  = k0 - cA * 24;          // in {0,8,16}
  const int bcol = b * BSTRIDE;
  const float* x2l = xall + (size_t)(1 + mpL) * XSTRIDE + bcol + d0;
  const float* x1l = xall + (size_t)1 * XSTRIDE + bcol + cA;

  // rolled pair loop (runtime bounds): R8's MP0-template + full unroll caused a
  // scratch-spill catastrophe (WRITE_SIZE 6->215 MB) — keep bounds runtime.
  for (int pi = p0; pi < p1; ++pi) {
    const int l1 = c_l1[OFF + pi], l2 = c_l2[OFF + pi];
    const int n1 = 2 * l1 + 1, n2 = 2 * l2 + 1;
    const int R1 = c_loff[l1], R2 = c_loff[l2];
    const int mK0w = mp0 + l1 + l2 - L;
    const int lo = mK0w - (n2 - 1);
    const int i0 = lo > 0 ? lo : 0;
    const int i1 = (n1 - 1) < (mK0w + 1) ? (n1 - 1) : (mK0w + 1);

    // prefetch bf16 B-fragments (L2-resident Wb); latency hides under diag loop
    const unsigned short* wbp = P.Wb + WBASE_C[L] + (size_t)pi * 18432 + lane * 8;
    const bf16x8 wfA0 = *(const bf16x8*)(wbp + kcA * 1024);
    const bf16x8 wfA1 = *(const bf16x8*)(wbp + kcA * 1024 + 512);
    const bf16x8 wfB0 = *(const bf16x8*)(wbp + (kcA + 3) * 1024);
    const bf16x8 wfB1 = *(const bf16x8*)(wbp + (kcA + 3) * 1024 + 512);
    const bf16x8 wfC0 = *(const bf16x8*)(wbp + (kcA + 6) * 1024);
    const bf16x8 wfC1 = *(const bf16x8*)(wbp + (kcA + 6) * 1024 + 512);

    f32x2 pA[4], pB[4], pC[4];
#pragma unroll
    for (int dd = 0; dd < 4; ++dd) {
      pA[dd] = (f32x2){0.f, 0.f};
      pB[dd] = (f32x2){0.f, 0.f};
      pC[dd] = (f32x2){0.f, 0.f};
    }

    const float* cgp = cgall + (mpL * NP + pi) * 12 + i0;
    const float* x2p = x2l + (size_t)(R2 + mK0w - i0) * XSTRIDE;
    const float* x1p = x1l + (size_t)(R1 + i0) * XSTRIDE;
    // j = mpL + mK0w - i in [-1, n2] -> guard rows cover; cg==0 kills invalid terms
    for (int i = i0; i <= i1; ++i) {
      const float cgv = *cgp++;
      f32x2 xv[4];
      *(f32x4*)&xv[0] = *(const f32x4*)x2p;
      *(f32x4*)&xv[2] = *(const f32x4*)(x2p + 4);
      const float sA = cgv * x1p[0];
      const float sB = cgv * x1p[4];
      const float sC = cgv * x1p[8];
      x2p -= XSTRIDE; x1p += XSTRIDE;
      const f32x2 svA = {sA, sA}, svB = {sB, sB}, svC = {sC, sC};
#pragma unroll
      for (int dd = 0; dd < 4; ++dd) {
        pA[dd] += svA * xv[dd];
        pB[dd] += svB * xv[dd];
        pC[dd] += svC * xv[dd];
      }
    }
    // pack A-fragments
    union { unsigned int u[4]; bf16x8 v; } zA, zB, zC;
#pragma unroll
    for (int dd = 0; dd < 4; ++dd) {
      union { __hip_bfloat162 h2; unsigned int u; } z;
      z.h2 = __float22bfloat162_rn(make_float2(pA[dd].x, pA[dd].y)); zA.u[dd] = z.u;
      z.h2 = __float22bfloat162_rn(make_float2(pB[dd].x, pB[dd].y)); zB.u[dd] = z.u;
      z.h2 = __float22bfloat162_rn(make_float2(pC[dd].x, pC[dd].y)); zC.u[dd] = z.u;
    }
    accC0 = __builtin_amdgcn_mfma_f32_16x16x32_bf16(zA.v, wfA0, accC0, 0, 0, 0);
    accC0 = __builtin_amdgcn_mfma_f32_16x16x32_bf16(zB.v, wfB0, accC0, 0, 0, 0);
    accC0 = __builtin_amdgcn_mfma_f32_16x16x32_bf16(zC.v, wfC0, accC0, 0, 0, 0);
    accC1 = __builtin_amdgcn_mfma_f32_16x16x32_bf16(zA.v, wfA1, accC1, 0, 0, 0);
    accC1 = __builtin_amdgcn_mfma_f32_16x16x32_bf16(zB.v, wfB1, accC1, 0, 0, 0);
    accC1 = __builtin_amdgcn_mfma_f32_16x16x32_bf16(zC.v, wfC1, accC1, 0, 0, 0);
  }

  __syncthreads();   // all xall reads done before red (alias) is written
  {
    const int col16 = lane & 15;      // D: col = h (lo half), row = (lane>>4)*4+reg
    const int rbase = w * 16 + (lane >> 4) * 4;
#pragma unroll
    for (int r = 0; r < 4; ++r) {
      red[(rbase + r) * 32 + col16]      = accC0[r];
      red[(rbase + r) * 32 + 16 + col16] = accC1[r];
    }
  }
  __syncthreads();
  for (int idx = t; idx < 512; idx += 384) {
    const int row = idx >> 5, h = idx & 31;   // 512: 16 rows x 32 h
    float v = 0.f;
#pragma unroll
    for (int ww = 0; ww < 6; ++ww) v += red[ww * 512 + row * 32 + h];
    const int ob = row & 7, omL = row >> 3;
    const int mp = mp0 + omL;
    if (mp <= 2 * L)
      atomicAdd(&P.out[(size_t)(b0 + ob) * 1152 + h * 36 + L * L + mp], v);
  }
}

__global__ __launch_bounds__(384, 5)
void CGLayer_main(Params P) {
  const int mb = blockIdx.x;
  const int l = c_mb_l[mb], mp0 = c_mb_m0[mb];
  const int btile = blockIdx.y >> 1;
  const int half  = blockIdx.y & 1;
  switch (l) {
    case 0: body<0>(P, mp0, btile, half); break;
    case 1: body<1>(P, mp0, btile, half); break;
    case 2: body<2>(P, mp0, btile, half); break;
    case 3: body<3>(P, mp0, btile, half); break;
    case 4: body<4>(P, mp0, btile, half); break;
    default: body<5>(P, mp0, btile, half); break;
  }
}

extern "C" void kernel_launch(void* const* d_in, const int* in_sizes, int n_in,
                              void* d_out, int out_size, void* d_ws, size_t ws_size,
                              hipStream_t stream) {
  Params P;
  for (int i = 0; i < 6; ++i) P.x[i] = (const float*)d_in[i];
  for (int i = 0; i < 6; ++i) P.W[i] = (const float*)d_in[6 + i];
  P.cg  = (const float*)d_in[12];
  P.out = (float*)d_out;
  P.Wb  = (unsigned short*)d_ws;   // needs 4,091,904 bytes

  hipMemsetAsync(d_out, 0, (size_t)out_size * sizeof(float), stream);
  dim3 sg(216, 6);
  swizzle_W<<<sg, 256, 0, stream>>>(P);
  dim3 grid(21, 64);               // y: btile*2 + pair-half
  CGLayer_main<<<grid, 384, SMEM_FLOATS * sizeof(float), stream>>>(P);
}

// Round 10
// 149.714 us; speedup vs baseline: 2.9140x; 1.0800x over previous
//
#include <hip/hip_runtime.h>
#include <hip/hip_bf16.h>

typedef __attribute__((ext_vector_type(8))) short bf16x8;
typedef __attribute__((ext_vector_type(4))) float f32x4;
typedef __attribute__((ext_vector_type(2))) float f32x2;

struct Params {
  const float* x[6];
  const float* W[6];
  const float* cg;
  float* out;
  unsigned short* Wb;   // ws: W pre-swizzled to bf16 B-fragment order (4,091,904 B)
};

constexpr int NPAIRS_C[6] = {6, 15, 21, 24, 24, 21};
constexpr int POFF_C[6]   = {0, 6, 21, 42, 66, 90};
constexpr size_t WBASE_C[6] = {0, 110592, 387072, 774144, 1216512, 1658880};
constexpr int KL_C[6]   = {3456, 8640, 12096, 13824, 13824, 12096};
#define XSTRIDE 116       // floats; %32==20, %4==0 (16B-aligned rows); BT=4 -> 4*28=112 cols
#define BSTRIDE 28        // b*28 mod 32 distinct per b
#define NGUARD 3          // j in [-3, n2+2] across 4 mpL values

__constant__ int c_l1[111] = {
  0,1,2,3,4,5,
  0,1,1,1,2,2,2,3,3,3,4,4,4,5,5,
  0,1,1,1,2,2,2,2,2,3,3,3,3,3,4,4,4,4,5,5,5,
  0,1,1,1,2,2,2,2,2,3,3,3,3,3,3,4,4,4,4,4,5,5,5,5,
  0,1,1,1,2,2,2,2,3,3,3,3,3,4,4,4,4,4,4,5,5,5,5,5,
  0,1,1,2,2,2,3,3,3,3,4,4,4,4,4,5,5,5,5,5,5
};
__constant__ int c_l2[111] = {
  0,1,2,3,4,5,
  1,0,1,2,1,2,3,2,3,4,3,4,5,4,5,
  2,1,2,3,0,1,2,3,4,1,2,3,4,5,2,3,4,5,3,4,5,
  3,2,3,4,1,2,3,4,5,0,1,2,3,4,5,1,2,3,4,5,2,3,4,5,
  4,3,4,5,2,3,4,5,1,2,3,4,5,0,1,2,3,4,5,1,2,3,4,5,
  5,4,5,3,4,5,2,3,4,5,1,2,3,4,5,0,1,2,3,4,5
};
__constant__ int c_loff[6] = {0, 1, 4, 9, 16, 25};
// 12 (L, mp0) combos, heaviest (NP*avg-diag) first; each covers mp0..mp0+3
__constant__ int c_mb_l[12]  = {4,4,4, 3,3, 5,5,5, 2,2, 1, 0};
__constant__ int c_mb_m0[12] = {0,4,8, 0,4, 0,4,8, 0,4, 0, 0};
// 3-chunk groups: wave w owns chunks {GA3[w], GA3[w]+3, GA3[w]+6} — same d0, c += 4, 8
__constant__ int c_GA3[6] = {0,1,2,9,10,11};

// ---------- W swizzle: fp32 [h][k] -> bf16 B-fragment stream (verified R4) ----------
template<int L>
__device__ __forceinline__ void swz(const Params& P, int u8) {
  constexpr int KL = KL_C[L];
  constexpr int KL8 = KL / 8;
  if (u8 >= 32 * KL8) return;
  const int h  = u8 / KL8;
  const int k  = (u8 - h * KL8) * 8;
  const int pair = k / 576;
  const int kin  = k - pair * 576;
  const int kc = kin >> 5;
  const int g  = (kin >> 3) & 3;
  const float* src = P.W[L] + (size_t)h * KL + k;
  f32x4 v0 = *(const f32x4*)src;
  f32x4 v1 = *(const f32x4*)(src + 4);
  union { __hip_bfloat162 h2; unsigned int u; } z;
  unsigned int o0, o1, o2, o3;
  z.h2 = __float22bfloat162_rn(make_float2(v0.x, v0.y)); o0 = z.u;
  z.h2 = __float22bfloat162_rn(make_float2(v0.z, v0.w)); o1 = z.u;
  z.h2 = __float22bfloat162_rn(make_float2(v1.x, v1.y)); o2 = z.u;
  z.h2 = __float22bfloat162_rn(make_float2(v1.z, v1.w)); o3 = z.u;
  const size_t dst = WBASE_C[L] + (size_t)pair * 18432 + kc * 1024 + (h >> 4) * 512
                   + ((size_t)(g * 16 + (h & 15))) * 8;
  *(uint4*)(P.Wb + dst) = make_uint4(o0, o1, o2, o3);
}

__global__ __launch_bounds__(256)
void swizzle_W(Params P) {
  const int u8 = blockIdx.x * 256 + threadIdx.x;
  switch (blockIdx.y) {
    case 0: swz<0>(P, u8); break;
    case 1: swz<1>(P, u8); break;
    case 2: swz<2>(P, u8); break;
    case 3: swz<3>(P, u8); break;
    case 4: swz<4>(P, u8); break;
    default: swz<5>(P, u8); break;
  }
}

// ---------- LDS layout (float units) ----------
// xall: [3 guard + 36 data + 3 guard rows][XSTRIDE] = 42*116 = 4872 floats
//   data row (l,i) = 3 + loff[l] + i; col = b*28 + c (b<4, c<24). Guard rows ZEROED.
// red ([6][16][32] = 3072 floats) ALIASES xall after the pair loop.
#define XALL_F 0
#define CG_F   4872       // [4][NP][12] f32 <= 1152
#define SMEM_FLOATS 6024  // 24,096 B -> 5+ blocks/CU (wave-cap limited)

template<int L>
__device__ __forceinline__ void body(const Params& P, const int mp0, const int btile) {
  constexpr int NP  = NPAIRS_C[L];
  constexpr int OFF = POFF_C[L];
  extern __shared__ float smem[];
  float* xall  = smem + XALL_F;
  float* cgall = smem + CG_F;
  float* red   = smem + XALL_F;          // alias (used only after barrier)

  const int t    = threadIdx.x;          // 384 threads = 6 waves
  const int lane = t & 63;
  const int w    = t >> 6;               // wave = 3-chunk group id (0..5)
  const int q8   = lane >> 4;            // A-frag k-quad
  const int rI   = lane & 15;            // A-frag row: b = rI&3, mpL = rI>>2
  const int b    = rI & 3;
  const int mpL  = rI >> 2;
  const int b0   = btile * 4;

  // ---- zero guard rows (0,1,2 and 39,40,41) ----
  for (int e = t; e < 6 * XSTRIDE; e += 384) {
    const int r = e / XSTRIDE;
    const int row = (r < 3) ? r : 36 + r;
    xall[row * XSTRIDE + (e - r * XSTRIDE)] = 0.f;
  }
  // ---- stage all x, transposed: xall[(3+loff[l]+i)*XSTRIDE + b*28 + c] ----
#pragma unroll
  for (int l = 0; l < 6; ++l) {
    const int n = 2 * l + 1;
    const float* src = P.x[l] + (size_t)b0 * 24 * n;
    const int tot = 4 * 24 * n;
    for (int e = t; e < tot; e += 384) {
      const int bc = e / n;                  // compile-time divisor
      const int i  = e - bc * n;
      const int bb = bc / 24;
      const int cc = bc - 24 * bb;
      xall[(NGUARD + c_loff[l] + i) * XSTRIDE + bb * BSTRIDE + cc] = src[e];
    }
  }
  // ---- stage cg diagonals for mp0..mp0+3 (zeros where invalid) ----
  for (int e = t; e < 4 * NP * 12; e += 384) {
    const int i  = e % 12;
    const int r  = e / 12;
    const int pi = r % NP;
    const int mL = r / NP;
    const int l1 = c_l1[OFF + pi], l2 = c_l2[OFF + pi];
    const int mp = mp0 + mL;
    const int j  = mp + l1 + l2 - L - i;
    float v = 0.f;
    if (mp <= 2 * L && i <= 2 * l1 && j >= 0 && j <= 2 * l2)
      v = P.cg[((size_t)(((l1 * 6 + l2) * 6 + L) * 11 + mp) * 11 + i) * 11 + j];
    cgall[(mL * NP + pi) * 12 + i] = v;
  }
  __syncthreads();

  f32x4 accC0 = {0.f, 0.f, 0.f, 0.f};   // h 0..15
  f32x4 accC1 = {0.f, 0.f, 0.f, 0.f};   // h 16..31

  // this wave's 3-chunk group
  const int kcA = c_GA3[w];
  const int k0  = kcA * 32 + q8 * 8;
  const int cA  = k0 / 24;
  const int d0  = k0 - cA * 24;          // in {0,8,16}
  const int bcol = b * BSTRIDE;
  const float* x2l = xall + (size_t)(NGUARD + mpL) * XSTRIDE + bcol + d0;
  const float* x1l = xall + (size_t)NGUARD * XSTRIDE + bcol + cA;

  for (int pi = 0; pi < NP; ++pi) {
    const int l1 = c_l1[OFF + pi], l2 = c_l2[OFF + pi];
    const int n1 = 2 * l1 + 1, n2 = 2 * l2 + 1;
    const int R1 = c_loff[l1], R2 = c_loff[l2];
    const int mK0w = mp0 + l1 + l2 - L;
    const int lo = mK0w - (n2 - 1);
    const int i0 = lo > 0 ? lo : 0;
    const int i1 = (n1 - 1) < (mK0w + 3) ? (n1 - 1) : (mK0w + 3);

    // prefetch bf16 B-fragments (L2-resident Wb); latency hides under diag loop
    const unsigned short* wbp = P.Wb + WBASE_C[L] + (size_t)pi * 18432 + lane * 8;
    const bf16x8 wfA0 = *(const bf16x8*)(wbp + kcA * 1024);
    const bf16x8 wfA1 = *(const bf16x8*)(wbp + kcA * 1024 + 512);
    const bf16x8 wfB0 = *(const bf16x8*)(wbp + (kcA + 3) * 1024);
    const bf16x8 wfB1 = *(const bf16x8*)(wbp + (kcA + 3) * 1024 + 512);
    const bf16x8 wfC0 = *(const bf16x8*)(wbp + (kcA + 6) * 1024);
    const bf16x8 wfC1 = *(const bf16x8*)(wbp + (kcA + 6) * 1024 + 512);

    f32x2 pA[4], pB[4], pC[4];
#pragma unroll
    for (int dd = 0; dd < 4; ++dd) {
      pA[dd] = (f32x2){0.f, 0.f};
      pB[dd] = (f32x2){0.f, 0.f};
      pC[dd] = (f32x2){0.f, 0.f};
    }

    const float* cgp = cgall + (mpL * NP + pi) * 12 + i0;
    const float* x2p = x2l + (size_t)(R2 + mK0w - i0) * XSTRIDE;
    const float* x1p = x1l + (size_t)(R1 + i0) * XSTRIDE;
    // j = mpL + mK0w - i in [-3, n2+2] -> guard rows cover; cg==0 kills invalid terms
    for (int i = i0; i <= i1; ++i) {
      const float cgv = *cgp++;
      f32x2 xv[4];
      *(f32x4*)&xv[0] = *(const f32x4*)x2p;
      *(f32x4*)&xv[2] = *(const f32x4*)(x2p + 4);
      const float sA = cgv * x1p[0];
      const float sB = cgv * x1p[4];
      const float sC = cgv * x1p[8];
      x2p -= XSTRIDE; x1p += XSTRIDE;
      const f32x2 svA = {sA, sA}, svB = {sB, sB}, svC = {sC, sC};
#pragma unroll
      for (int dd = 0; dd < 4; ++dd) {
        pA[dd] += svA * xv[dd];
        pB[dd] += svB * xv[dd];
        pC[dd] += svC * xv[dd];
      }
    }
    // pack A-fragments
    union { unsigned int u[4]; bf16x8 v; } zA, zB, zC;
#pragma unroll
    for (int dd = 0; dd < 4; ++dd) {
      union { __hip_bfloat162 h2; unsigned int u; } z;
      z.h2 = __float22bfloat162_rn(make_float2(pA[dd].x, pA[dd].y)); zA.u[dd] = z.u;
      z.h2 = __float22bfloat162_rn(make_float2(pB[dd].x, pB[dd].y)); zB.u[dd] = z.u;
      z.h2 = __float22bfloat162_rn(make_float2(pC[dd].x, pC[dd].y)); zC.u[dd] = z.u;
    }
    accC0 = __builtin_amdgcn_mfma_f32_16x16x32_bf16(zA.v, wfA0, accC0, 0, 0, 0);
    accC0 = __builtin_amdgcn_mfma_f32_16x16x32_bf16(zB.v, wfB0, accC0, 0, 0, 0);
    accC0 = __builtin_amdgcn_mfma_f32_16x16x32_bf16(zC.v, wfC0, accC0, 0, 0, 0);
    accC1 = __builtin_amdgcn_mfma_f32_16x16x32_bf16(zA.v, wfA1, accC1, 0, 0, 0);
    accC1 = __builtin_amdgcn_mfma_f32_16x16x32_bf16(zB.v, wfB1, accC1, 0, 0, 0);
    accC1 = __builtin_amdgcn_mfma_f32_16x16x32_bf16(zC.v, wfC1, accC1, 0, 0, 0);
  }

  __syncthreads();   // all xall reads done before red (alias) is written
  {
    const int col16 = lane & 15;      // D: col = h (lo half), row = (lane>>4)*4+reg
    const int rbase = w * 16 + (lane >> 4) * 4;
#pragma unroll
    for (int r = 0; r < 4; ++r) {
      red[(rbase + r) * 32 + col16]      = accC0[r];
      red[(rbase + r) * 32 + 16 + col16] = accC1[r];
    }
  }
  __syncthreads();
  for (int idx = t; idx < 512; idx += 384) {
    const int row = idx >> 5, h = idx & 31;   // 512: 16 rows (4b x 4mp) x 32 h
    float v = 0.f;
#pragma unroll
    for (int ww = 0; ww < 6; ++ww) v += red[ww * 512 + row * 32 + h];
    const int ob = row & 3, omL = row >> 2;
    const int mp = mp0 + omL;
    if (mp <= 2 * L)
      P.out[(size_t)(b0 + ob) * 1152 + h * 36 + L * L + mp] = v;
  }
}

__global__ __launch_bounds__(384, 6)
void CGLayer_main(Params P) {
  const int mb = blockIdx.x;
  const int l = c_mb_l[mb], mp0 = c_mb_m0[mb];
  const int btile = blockIdx.y;
  switch (l) {
    case 0: body<0>(P, mp0, btile); break;
    case 1: body<1>(P, mp0, btile); break;
    case 2: body<2>(P, mp0, btile); break;
    case 3: body<3>(P, mp0, btile); break;
    case 4: body<4>(P, mp0, btile); break;
    default: body<5>(P, mp0, btile); break;
  }
}

extern "C" void kernel_launch(void* const* d_in, const int* in_sizes, int n_in,
                              void* d_out, int out_size, void* d_ws, size_t ws_size,
                              hipStream_t stream) {
  Params P;
  for (int i = 0; i < 6; ++i) P.x[i] = (const float*)d_in[i];
  for (int i = 0; i < 6; ++i) P.W[i] = (const float*)d_in[6 + i];
  P.cg  = (const float*)d_in[12];
  P.out = (float*)d_out;
  P.Wb  = (unsigned short*)d_ws;   // needs 4,091,904 bytes

  dim3 sg(216, 6);
  swizzle_W<<<sg, 256, 0, stream>>>(P);
  dim3 grid(12, 64);               // 768 blocks = exactly 3 blocks/CU
  CGLayer_main<<<grid, 384, SMEM_FLOATS * sizeof(float), stream>>>(P);
}